// Round 25
// baseline (1861.751 us; speedup 1.0000x reference)
//
#include <hip/hip_runtime.h>
#include <math.h>

// ROUND 25: attn S-phase onto the f64 matrix pipe, reusing the runtime-
// calibrated g_qk_mode (proven by r23/r24 passes). Q held in registers as
// A-fragments; per k-tile MFMA S -> mode-switched dump to LDS Sd[k][q] ->
// mode-independent softmax identical in structure/formulas to r24 -> fp32 PV.
// LDS: KVd 33.8KB (Sd 16.9KB + Vf 16KB alias after S) + Ps 8.4KB = 42KB
// -> 3 blocks/CU (was 2). qk_calib/qk_gemm/v_gemm/proj unchanged from r24.

typedef double f64x4 __attribute__((ext_vector_type(4)));

__device__ int g_qk_mode;

// ---------------- K0: one-wave layout calibration (unchanged) ----------------
__global__ void qk_calib(const float* __restrict__ X, const float* __restrict__ W)
{
  __shared__ double As[16][66];
  __shared__ double Bs[16][66];
  const int t = threadIdx.x;            // 64 threads = 1 wave
  const int lm = t & 15, l4 = t >> 4;
  for (int p = 0; p < 16; ++p) {
    int f = p * 64 + t;
    int k = f >> 6, m = f & 63;
    As[k][m] = (double)X[(size_t)m * 1024 + k];
    Bs[k][m] = (double)W[(size_t)k * 3072 + m];
  }
  __syncthreads();
  f64x4 acc = {0., 0., 0., 0.};
#pragma unroll
  for (int k0 = 0; k0 < 16; k0 += 4) {
    double a = As[k0 + l4][lm];
    double b = Bs[k0 + l4][lm];
    acc = __builtin_amdgcn_mfma_f64_16x16x4f64(a, b, acc, 0, 0, 0);
  }
  double ref00 = 0., ref01 = 0., ref10 = 0., ref40 = 0., ref04 = 0.;
#pragma unroll
  for (int kk = 0; kk < 16; ++kk) {
    double a0 = As[kk][0], a1 = As[kk][1], a4 = As[kk][4];
    double b0 = Bs[kk][0], b1 = Bs[kk][1], b4 = Bs[kk][4];
    ref00 = fma(a0, b0, ref00);
    ref01 = fma(a0, b1, ref01);
    ref10 = fma(a1, b0, ref10);
    ref40 = fma(a4, b0, ref40);
    ref04 = fma(a0, b4, ref04);
  }
  double v00 = __shfl(acc[0], 0);
  double v16 = __shfl(acc[0], 16);
  if (t == 0) {
    int m;
    if (fabs(v00 - ref00) > 1e-5) {
      m = 0;
    } else {
      double d1 = fabs(v16 - ref40);
      double d2 = fabs(v16 - ref10);
      double d3 = fabs(v16 - ref04);
      double d4 = fabs(v16 - ref01);
      m = 1; double best = d1;
      if (d2 < best) { best = d2; m = 2; }
      if (d3 < best) { best = d3; m = 3; }
      if (d4 < best) { best = d4; m = 4; }
    }
    g_qk_mode = m;
  }
}

// ---------------- K1: q,k GEMM fp64 MFMA (unchanged from r24) ----------------
__global__ __launch_bounds__(256) void qk_gemm_f64(
    const float* __restrict__ X, const float* __restrict__ W,
    const float* __restrict__ bias,
    double* __restrict__ qT, double* __restrict__ kT, int b0)
{
  __shared__ double As[16][66];
  __shared__ double Bs[16][66];
  const int t = threadIdx.x;
  const int lane = t & 63, w = t >> 6;
  const int lm = lane & 15, l4 = lane >> 4;
  const int m0w = (w & 1) * 32, n0w = (w >> 1) * 32;
  const int n0 = blockIdx.x * 64;
  const int m0 = blockIdx.y * 64;
  const int mode = g_qk_mode;
  f64x4 acc00 = {0.,0.,0.,0.}, acc01 = {0.,0.,0.,0.};
  f64x4 acc10 = {0.,0.,0.,0.}, acc11 = {0.,0.,0.,0.};
  const size_t xrow0 = (size_t)b0 * 1024 + m0;

  if (mode != 0) {
    for (int k0t = 0; k0t < 1024; k0t += 16) {
      __syncthreads();
      {
        int r = t >> 2, kq = (t & 3) << 2;
        float4 xv = *(const float4*)&X[(xrow0 + r) * 1024 + k0t + kq];
        As[kq + 0][r] = (double)xv.x;
        As[kq + 1][r] = (double)xv.y;
        As[kq + 2][r] = (double)xv.z;
        As[kq + 3][r] = (double)xv.w;
        int kr = t >> 4, cq = (t & 15) << 2;
        float4 wv = *(const float4*)&W[(size_t)(k0t + kr) * 3072 + n0 + cq];
        Bs[kr][cq + 0] = (double)wv.x;
        Bs[kr][cq + 1] = (double)wv.y;
        Bs[kr][cq + 2] = (double)wv.z;
        Bs[kr][cq + 3] = (double)wv.w;
      }
      __syncthreads();
#pragma unroll
      for (int k0 = 0; k0 < 16; k0 += 4) {
        double a0 = As[k0 + l4][m0w + lm];
        double a1 = As[k0 + l4][m0w + 16 + lm];
        double bb0 = Bs[k0 + l4][n0w + lm];
        double bb1 = Bs[k0 + l4][n0w + 16 + lm];
        acc00 = __builtin_amdgcn_mfma_f64_16x16x4f64(a0, bb0, acc00, 0, 0, 0);
        acc01 = __builtin_amdgcn_mfma_f64_16x16x4f64(a0, bb1, acc01, 0, 0, 0);
        acc10 = __builtin_amdgcn_mfma_f64_16x16x4f64(a1, bb0, acc10, 0, 0, 0);
        acc11 = __builtin_amdgcn_mfma_f64_16x16x4f64(a1, bb1, acc11, 0, 0, 0);
      }
    }
  }

  double* T = (n0 < 1024) ? qT : kT;
  const int nn = n0 & 1023;
  const int h = nn >> 6;
  const int bl = m0 >> 10;
  const int sb = m0 & 1023;
  const size_t hb = (size_t)(bl * 16 + h) * 64;

  if (mode != 0) {
#pragma unroll
    for (int ni = 0; ni < 2; ++ni) {
#pragma unroll
      for (int mi = 0; mi < 2; ++mi) {
        f64x4 av = ni ? (mi ? acc11 : acc01) : (mi ? acc10 : acc00);
        if (mode <= 2) {
          const int d = n0w + 16 * ni + lm;
          const double bz = (double)bias[n0 + d];
          const size_t cb = ((hb + d) << 10) + sb;
#pragma unroll
          for (int r = 0; r < 4; ++r) {
            int row = m0w + 16 * mi + ((mode == 1) ? (4 * l4 + r) : (l4 + 4 * r));
            T[cb + row] = av[r] + bz;
          }
        } else {
          const int row = m0w + 16 * mi + lm;
#pragma unroll
          for (int r = 0; r < 4; ++r) {
            int d = n0w + 16 * ni + ((mode == 3) ? (4 * l4 + r) : (l4 + 4 * r));
            T[((hb + d) << 10) + sb + row] = av[r] + (double)bias[n0 + d];
          }
        }
      }
    }
  } else {
    double accv[2][8];
#pragma unroll
    for (int i = 0; i < 2; ++i)
#pragma unroll
      for (int j = 0; j < 8; ++j) accv[i][j] = 0.;
    for (int k0t = 0; k0t < 1024; k0t += 16) {
      __syncthreads();
      {
        int r = t >> 2, kq = (t & 3) << 2;
        float4 xv = *(const float4*)&X[(xrow0 + r) * 1024 + k0t + kq];
        As[kq + 0][r] = (double)xv.x;
        As[kq + 1][r] = (double)xv.y;
        As[kq + 2][r] = (double)xv.z;
        As[kq + 3][r] = (double)xv.w;
        int kr = t >> 4, cq = (t & 15) << 2;
        float4 wv = *(const float4*)&W[(size_t)(k0t + kr) * 3072 + n0 + cq];
        Bs[kr][cq + 0] = (double)wv.x;
        Bs[kr][cq + 1] = (double)wv.y;
        Bs[kr][cq + 2] = (double)wv.z;
        Bs[kr][cq + 3] = (double)wv.w;
      }
      __syncthreads();
#pragma unroll
      for (int kk = 0; kk < 16; ++kk) {
        double a0 = As[kk][m0w + lm];
        double a1 = As[kk][m0w + 16 + lm];
#pragma unroll
        for (int j = 0; j < 8; ++j) {
          double bb = Bs[kk][n0w + 8 * l4 + j];
          accv[0][j] = fma(a0, bb, accv[0][j]);
          accv[1][j] = fma(a1, bb, accv[1][j]);
        }
      }
    }
#pragma unroll
    for (int j = 0; j < 8; ++j) {
      const int d = n0w + 8 * l4 + j;
      const double bz = (double)bias[n0 + d];
      const size_t cb = ((hb + d) << 10) + sb;
      T[cb + m0w + lm]      = accv[0][j] + bz;
      T[cb + m0w + 16 + lm] = accv[1][j] + bz;
    }
  }
}

// ---------------- K2: v GEMM fp32, 128x128 tile (unchanged) ----------------
__global__ __launch_bounds__(256) void v_gemm_f32(
    const float* __restrict__ X, const float* __restrict__ W,
    const float* __restrict__ bias, float* __restrict__ Vp, int b0)
{
  __shared__ __align__(16) float As[16][132];
  __shared__ __align__(16) float Bs[16][132];
  const int t = threadIdx.x, tx = t & 15, ty = t >> 4;
  const int n0 = blockIdx.x * 128;
  const int m0 = blockIdx.y * 128;
  float acc[2][2][4][4] = {};
  const size_t xrow0 = (size_t)b0 * 1024 + m0;

  for (int k0 = 0; k0 < 1024; k0 += 16) {
    __syncthreads();
#pragma unroll
    for (int p = 0; p < 2; ++p) {
      int f = p * 256 + t;
      int r = f >> 2, kq = (f & 3) << 2;
      float4 xv = *(const float4*)&X[(xrow0 + r) * 1024 + k0 + kq];
      As[kq + 0][r] = xv.x; As[kq + 1][r] = xv.y;
      As[kq + 2][r] = xv.z; As[kq + 3][r] = xv.w;
      int kr = f >> 5, cq = (f & 31) << 2;
      *(float4*)&Bs[kr][cq] = *(const float4*)&W[(size_t)(k0 + kr) * 3072 + 2048 + n0 + cq];
    }
    __syncthreads();
#pragma unroll
    for (int kk = 0; kk < 16; ++kk) {
      float4 A0 = *(const float4*)&As[kk][4 * ty];
      float4 A1 = *(const float4*)&As[kk][64 + 4 * ty];
      float4 B0 = *(const float4*)&Bs[kk][4 * tx];
      float4 B1 = *(const float4*)&Bs[kk][64 + 4 * tx];
      float a[2][4] = {{A0.x, A0.y, A0.z, A0.w}, {A1.x, A1.y, A1.z, A1.w}};
      float b[2][4] = {{B0.x, B0.y, B0.z, B0.w}, {B1.x, B1.y, B1.z, B1.w}};
#pragma unroll
      for (int ri = 0; ri < 2; ++ri)
#pragma unroll
        for (int i = 0; i < 4; ++i)
#pragma unroll
          for (int ci = 0; ci < 2; ++ci)
#pragma unroll
            for (int j = 0; j < 4; ++j)
              acc[ri][ci][i][j] = fmaf(a[ri][i], b[ci][j], acc[ri][ci][i][j]);
    }
  }
  const int bl = m0 >> 10;
  const int sb = m0 & 1023;
#pragma unroll
  for (int ci = 0; ci < 2; ++ci) {
    int h = (n0 >> 6) + ci;
    float bz[4];
#pragma unroll
    for (int j = 0; j < 4; ++j) bz[j] = bias[2048 + n0 + 64 * ci + 4 * tx + j];
#pragma unroll
    for (int ri = 0; ri < 2; ++ri)
#pragma unroll
      for (int i = 0; i < 4; ++i) {
        int s = sb + 64 * ri + 4 * ty + i;
        float4 vv = make_float4(acc[ri][ci][i][0] + bz[0], acc[ri][ci][i][1] + bz[1],
                                acc[ri][ci][i][2] + bz[2], acc[ri][ci][i][3] + bz[3]);
        *(float4*)&Vp[((size_t)(bl * 16 + h) * 1024 + s) * 64 + 4 * tx] = vv;
      }
  }
}

// ---------------- K3: fused attention v3 — MFMA S-phase ----------------
// 256 thr, q-block 32, k-tile 64. Wave w computes S[q 0..31][k 16w..16w+15]
// via 2 q-tiles x 16 d-steps of mfma_f64_16x16x4 (Q A-frags in registers).
// D dumped to Sd[k][33q-pitch] via the SAME mode-switched formulas as qk's
// store; softmax/PV identical in formulas to r24 with k-ownership tx+16j.
__global__ __launch_bounds__(256) void attn_fused(
    const double* __restrict__ qT, const double* __restrict__ kT,
    const float* __restrict__ Vp, const float* __restrict__ Mask,
    float* __restrict__ AO, int b0)
{
  __shared__ double KVd[64][66];              // K tile [d][k] (33792 B)
  __shared__ float  Ps[32][66];               // P tile   (8448 B)
  double* Sd = &KVd[0][0];                    // alias: [64 k][33 q] f64 (16896 B)
  float*  Vf = (float*)((char*)&KVd[0][0] + 16896);   // alias: [64 k][64 d] f32

  const int t = threadIdx.x;
  const int lane = t & 63, w = t >> 6;        // wave 0..3 -> k-range 16w
  const int lm = lane & 15, l4 = lane >> 4;
  const int tx = t & 15, ty = t >> 4;         // softmax/PV: q {2ty,2ty+1}, k {tx+16j}
  const int bh = blockIdx.y;
  const int bl = bh >> 4, h = bh & 15;
  const int bg = b0 + bl;
  const int q0 = blockIdx.x * 32;
  const double* qTb = qT + (size_t)bh * 65536;
  const double* kTb = kT + (size_t)bh * 65536;
  const float*  Vb  = Vp + (size_t)bh * 65536;
  const float*  mb  = Mask + (size_t)bg * 1048576 + (size_t)q0 * 1024;
  const int mode = g_qk_mode;

  // A-fragments: qreg[qt][s] = Q[q0 + 16qt + lm][d = 4s + l4]
  double qreg[2][16];
#pragma unroll
  for (int qt = 0; qt < 2; ++qt)
#pragma unroll
    for (int s = 0; s < 16; ++s)
      qreg[qt][s] = qTb[(size_t)(4 * s + l4) * 1024 + q0 + 16 * qt + lm];

  double Mreg[2] = {-1e300, -1e300};
  float Lreg[2] = {0.f, 0.f};
  float o[2][4] = {};

  for (int kt = 0; kt < 16; ++kt) {
    const int k0 = kt * 64;
    __syncthreads();                          // A: prev PV/Sd reads done
    // stage K [d][k]
#pragma unroll
    for (int p = 0; p < 8; ++p) {
      int f = p * 256 + t;
      int d = f >> 5, c = f & 31;
      *(double2*)&KVd[d][2 * c] = *(const double2*)&kTb[(size_t)d * 1024 + k0 + 2 * c];
    }
    __syncthreads();                          // B: K staged

    f64x4 acc0 = {0., 0., 0., 0.}, acc1 = {0., 0., 0., 0.};
    double sv[2][4];
    if (mode != 0) {
#pragma unroll
      for (int s = 0; s < 16; ++s) {
        double b = KVd[4 * s + l4][16 * w + lm];
        acc0 = __builtin_amdgcn_mfma_f64_16x16x4f64(qreg[0][s], b, acc0, 0, 0, 0);
        acc1 = __builtin_amdgcn_mfma_f64_16x16x4f64(qreg[1][s], b, acc1, 0, 0, 0);
      }
    } else {
      // fallback: VALU S into regs (reads KVd; Q broadcast from global/L2)
#pragma unroll
      for (int i = 0; i < 2; ++i)
#pragma unroll
        for (int j = 0; j < 4; ++j) sv[i][j] = 0.;
      for (int d = 0; d < 64; ++d) {
        double qv0 = qTb[(size_t)d * 1024 + q0 + 2 * ty];
        double qv1 = qTb[(size_t)d * 1024 + q0 + 2 * ty + 1];
#pragma unroll
        for (int j = 0; j < 4; ++j) {
          double kv = KVd[d][tx + 16 * j];
          sv[0][j] = fma(qv0, kv, sv[0][j]);
          sv[1][j] = fma(qv1, kv, sv[1][j]);
        }
      }
    }
    __syncthreads();                          // C: all KVd reads done

    // write S -> Sd[k][q] (mode-switched, mirrors qk store) + stage V
    if (mode != 0) {
      const int nof = 16 * w;
#pragma unroll
      for (int qt = 0; qt < 2; ++qt) {
        f64x4 av = qt ? acc1 : acc0;
        if (mode <= 2) {
          const int k = nof + lm;
#pragma unroll
          for (int r = 0; r < 4; ++r) {
            int q = 16 * qt + ((mode == 1) ? (4 * l4 + r) : (l4 + 4 * r));
            Sd[k * 33 + q] = av[r];
          }
        } else {
          const int q = 16 * qt + lm;
#pragma unroll
          for (int r = 0; r < 4; ++r) {
            int k = nof + ((mode == 3) ? (4 * l4 + r) : (l4 + 4 * r));
            Sd[k * 33 + q] = av[r];
          }
        }
      }
    } else {
#pragma unroll
      for (int i = 0; i < 2; ++i)
#pragma unroll
        for (int j = 0; j < 4; ++j)
          Sd[(tx + 16 * j) * 33 + 2 * ty + i] = sv[i][j];
    }
#pragma unroll
    for (int p = 0; p < 4; ++p) {
      int f = p * 256 + t;
      *(float4*)&Vf[4 * f] = *(const float4*)&Vb[(size_t)k0 * 64 + 4 * f];
    }
    __syncthreads();                          // D: Sd + Vf ready

    // softmax (formulas identical to r24; k strided tx+16j)
    float al[2];
#pragma unroll
    for (int i = 0; i < 2; ++i) {
      const int q = 2 * ty + i;
      double z[4];
#pragma unroll
      for (int j = 0; j < 4; ++j) {
        int k = tx + 16 * j;
        double s = Sd[k * 33 + q];
        float mv = mb[(size_t)q * 1024 + k0 + k];
        z[j] = (mv != 0.f) ? s * -1.25e8 : 0.0;
      }
      double mx = fmax(fmax(z[0], z[1]), fmax(z[2], z[3]));
#pragma unroll
      for (int ww = 1; ww < 16; ww <<= 1) mx = fmax(mx, __shfl_xor(mx, ww));
      double nM = fmax(Mreg[i], mx);
      double da = Mreg[i] - nM;
      al[i] = (da < -80.0) ? 0.f : expf((float)da);
      float p0, p1, p2, p3;
      {
        double d0 = z[0] - nM, d1 = z[1] - nM, d2 = z[2] - nM, d3 = z[3] - nM;
        p0 = (d0 < -80.0) ? 0.f : expf((float)d0);
        p1 = (d1 < -80.0) ? 0.f : expf((float)d1);
        p2 = (d2 < -80.0) ? 0.f : expf((float)d2);
        p3 = (d3 < -80.0) ? 0.f : expf((float)d3);
      }
      float ps = ((p0 + p1) + p2) + p3;
#pragma unroll
      for (int ww = 1; ww < 16; ww <<= 1) ps += __shfl_xor(ps, ww);
      Lreg[i] = Lreg[i] * al[i] + ps;
      Mreg[i] = nM;
      Ps[q][tx +  0] = p0;
      Ps[q][tx + 16] = p1;
      Ps[q][tx + 32] = p2;
      Ps[q][tx + 48] = p3;
    }
    __syncthreads();                          // E: Ps complete

    // PV (fp32, kk ascending)
#pragma unroll
    for (int i = 0; i < 2; ++i) {
      o[i][0] *= al[i]; o[i][1] *= al[i]; o[i][2] *= al[i]; o[i][3] *= al[i];
    }
#pragma unroll 4
    for (int kk = 0; kk < 64; kk += 4) {
      float4 vv0 = *(const float4*)&Vf[(kk + 0) * 64 + 4 * tx];
      float4 vv1 = *(const float4*)&Vf[(kk + 1) * 64 + 4 * tx];
      float4 vv2 = *(const float4*)&Vf[(kk + 2) * 64 + 4 * tx];
      float4 vv3 = *(const float4*)&Vf[(kk + 3) * 64 + 4 * tx];
#pragma unroll
      for (int i = 0; i < 2; ++i) {
        const int q = 2 * ty + i;
        float pa0 = Ps[q][kk + 0];
        float pa1 = Ps[q][kk + 1];
        float pa2 = Ps[q][kk + 2];
        float pa3 = Ps[q][kk + 3];
        o[i][0] = fmaf(pa0, vv0.x, o[i][0]);
        o[i][0] = fmaf(pa1, vv1.x, o[i][0]);
        o[i][0] = fmaf(pa2, vv2.x, o[i][0]);
        o[i][0] = fmaf(pa3, vv3.x, o[i][0]);
        o[i][1] = fmaf(pa0, vv0.y, o[i][1]);
        o[i][1] = fmaf(pa1, vv1.y, o[i][1]);
        o[i][1] = fmaf(pa2, vv2.y, o[i][1]);
        o[i][1] = fmaf(pa3, vv3.y, o[i][1]);
        o[i][2] = fmaf(pa0, vv0.z, o[i][2]);
        o[i][2] = fmaf(pa1, vv1.z, o[i][2]);
        o[i][2] = fmaf(pa2, vv2.z, o[i][2]);
        o[i][2] = fmaf(pa3, vv3.z, o[i][2]);
        o[i][3] = fmaf(pa0, vv0.w, o[i][3]);
        o[i][3] = fmaf(pa1, vv1.w, o[i][3]);
        o[i][3] = fmaf(pa2, vv2.w, o[i][3]);
        o[i][3] = fmaf(pa3, vv3.w, o[i][3]);
      }
    }
  }
#pragma unroll
  for (int i = 0; i < 2; ++i) {
    const int q = 2 * ty + i;
    float inv = (Lreg[i] > 0.f) ? 1.f / Lreg[i] : 0.f;
    float4 vv = make_float4(o[i][0] * inv, o[i][1] * inv, o[i][2] * inv, o[i][3] * inv);
    *(float4*)&AO[(size_t)(bl * 1024 + q0 + q) * 1024 + h * 64 + 4 * tx] = vv;
  }
}

// ---------------- K4: output projection fp32 (unchanged) ----------------
__global__ __launch_bounds__(256) void proj_gemm(
    const float* __restrict__ AO, const float* __restrict__ W,
    const float* __restrict__ bias, float* __restrict__ Out, int b0)
{
  __shared__ __align__(16) float As[16][132];
  __shared__ __align__(16) float Bs[16][132];
  const int t = threadIdx.x, tx = t & 15, ty = t >> 4;
  const int n0 = blockIdx.x * 128;
  const int m0l = blockIdx.y * 128;
  float acc[2][2][4][4] = {};

  for (int k0 = 0; k0 < 1024; k0 += 16) {
    __syncthreads();
#pragma unroll
    for (int p = 0; p < 2; ++p) {
      int f = p * 256 + t;
      int r = f >> 2, kq = (f & 3) << 2;
      float4 av = *(const float4*)&AO[(size_t)(m0l + r) * 1024 + k0 + kq];
      As[kq + 0][r] = av.x; As[kq + 1][r] = av.y;
      As[kq + 2][r] = av.z; As[kq + 3][r] = av.w;
      int kr = f >> 5, cq = (f & 31) << 2;
      *(float4*)&Bs[kr][cq] = *(const float4*)&W[(size_t)(k0 + kr) * 1024 + n0 + cq];
    }
    __syncthreads();
#pragma unroll
    for (int kk = 0; kk < 16; ++kk) {
      float4 A0 = *(const float4*)&As[kk][4 * ty];
      float4 A1 = *(const float4*)&As[kk][64 + 4 * ty];
      float4 B0 = *(const float4*)&Bs[kk][4 * tx];
      float4 B1 = *(const float4*)&Bs[kk][64 + 4 * tx];
      float a[2][4] = {{A0.x, A0.y, A0.z, A0.w}, {A1.x, A1.y, A1.z, A1.w}};
      float b[2][4] = {{B0.x, B0.y, B0.z, B0.w}, {B1.x, B1.y, B1.z, B1.w}};
#pragma unroll
      for (int ri = 0; ri < 2; ++ri)
#pragma unroll
        for (int i = 0; i < 4; ++i)
#pragma unroll
          for (int ci = 0; ci < 2; ++ci)
#pragma unroll
            for (int j = 0; j < 4; ++j)
              acc[ri][ci][i][j] = fmaf(a[ri][i], b[ci][j], acc[ri][ci][i][j]);
    }
  }
#pragma unroll
  for (int ci = 0; ci < 2; ++ci) {
    float bz[4];
#pragma unroll
    for (int j = 0; j < 4; ++j) bz[j] = bias[n0 + 64 * ci + 4 * tx + j];
#pragma unroll
    for (int ri = 0; ri < 2; ++ri)
#pragma unroll
      for (int i = 0; i < 4; ++i) {
        float4 vv = make_float4(acc[ri][ci][i][0] + bz[0], acc[ri][ci][i][1] + bz[1],
                                acc[ri][ci][i][2] + bz[2], acc[ri][ci][i][3] + bz[3]);
        size_t row = (size_t)b0 * 1024 + m0l + 64 * ri + 4 * ty + i;
        *(float4*)&Out[row * 1024 + n0 + 64 * ci + 4 * tx] = vv;
      }
  }
}

extern "C" void kernel_launch(void* const* d_in, const int* in_sizes, int n_in,
                              void* d_out, int out_size, void* d_ws, size_t ws_size,
                              hipStream_t stream) {
  (void)in_sizes; (void)n_in; (void)out_size;
  const float* x      = (const float*)d_in[0];
  const float* mask   = (const float*)d_in[1];
  const float* W_attn = (const float*)d_in[2];
  const float* b_attn = (const float*)d_in[3];
  const float* W_proj = (const float*)d_in[4];
  const float* b_proj = (const float*)d_in[5];
  float* out = (float*)d_out;

  int CB = (ws_size >= (192ull << 20)) ? 8
         : (ws_size >= (96ull  << 20)) ? 4
         : (ws_size >= (48ull  << 20)) ? 2 : 1;

  char* base = (char*)d_ws;
  double* qT = (double*)base;
  double* kT = (double*)(base + (size_t)CB * (8ull  << 20));
  float*  Vp = (float*)(base + (size_t)CB * (16ull << 20));
  float*  AO = (float*)(base + (size_t)CB * (20ull << 20));

  qk_calib<<<1, 64, 0, stream>>>(x, W_attn);
  for (int b0 = 0; b0 < 8; b0 += CB) {
    qk_gemm_f64<<<dim3(32, 16 * CB), 256, 0, stream>>>(x, W_attn, b_attn, qT, kT, b0);
    v_gemm_f32<<<dim3(8, 8 * CB), 256, 0, stream>>>(x, W_attn, b_attn, Vp, b0);
    attn_fused<<<dim3(32, 16 * CB), 256, 0, stream>>>(qT, kT, Vp, mask, AO, b0);
    proj_gemm<<<dim3(8, 8 * CB), 256, 0, stream>>>(AO, W_proj, b_proj, out, b0);
  }
}